// Round 1
// 1600.762 us; speedup vs baseline: 1.0927x; 1.0927x over previous
//
#include <hip/hip_runtime.h>

#define NN 16384
#define DIN 512
#define DOUT 128
#define SPLITK 2
#define KHALF (NN / SPLITK)   // 8192 k per split block
#define NK32 (KHALF / 32)     // 256 k-steps of 32

typedef __bf16 bf16x8 __attribute__((ext_vector_type(8)));
typedef float floatx4 __attribute__((ext_vector_type(4)));

__device__ __forceinline__ unsigned short f2bf(float f) {
    unsigned u = __builtin_bit_cast(unsigned, f);
    u += 0x7FFFu + ((u >> 16) & 1u);   // RNE
    return (unsigned short)(u >> 16);
}

__device__ __forceinline__ unsigned pk2(float lo, float hi) {
    return (unsigned)f2bf(lo) | ((unsigned)f2bf(hi) << 16);
}

// ---------------------------------------------------------------------------
// Kernel 1: x = inputs @ W, fp32 accum, output written as bf16 in MFMA
// B-FRAGMENT ORDER so kernel 2 needs no LDS at all:
//   uint4 index = (k32*8 + d/16)*64 + lane,  lane = ((n>>3)&3)*16 + (d&15),
//   bytes within uint4 = (n&7)*2.   (k32 = n>>5)
// Block = 256 thr, tile = 32 n x 128 d. Thread (ng=tid>>6, dp=tid&63) owns
// n = n0+ng*8+i (i=0..7), d = 2*dp+j (j=0..1)  -> stores are two full uint4.
// Inputs tile staged TRANSPOSED (sInT[c][n]) so the a-reads are wave-uniform
// ds_read_b128 broadcasts (free).
// ---------------------------------------------------------------------------
__global__ __launch_bounds__(256) void xw_kernel(
        const float* __restrict__ inp, const float* __restrict__ w,
        unsigned short* __restrict__ xTf) {
    __shared__ float sInT[64][36];   // [c][n]; 36 keeps b128 16B-alignment
    __shared__ float sW[64][128];
    const int tid = threadIdx.x;
    const int n0 = blockIdx.x * 32;
    const int ng = tid >> 6;   // wave id = n-octet 0..3
    const int dp = tid & 63;   // d-pair 0..63

    float acc[8][2];
#pragma unroll
    for (int i = 0; i < 8; ++i) { acc[i][0] = 0.f; acc[i][1] = 0.f; }

    for (int c0 = 0; c0 < DIN; c0 += 64) {
        __syncthreads();
        // stage inputs tile 32n x 64c, transposed into sInT[c][n]
#pragma unroll
        for (int p = 0; p < 2; ++p) {
            int s = tid + p * 256;
            int row = s >> 4;            // n row 0..31
            int c4 = (s & 15) << 2;      // c 0,4,..60
            float4 v = *(const float4*)&inp[(size_t)(n0 + row) * DIN + c0 + c4];
            sInT[c4 + 0][row] = v.x;
            sInT[c4 + 1][row] = v.y;
            sInT[c4 + 2][row] = v.z;
            sInT[c4 + 3][row] = v.w;
        }
        // stage W tile 64c x 128d
#pragma unroll
        for (int p = 0; p < 8; ++p) {
            int s = tid + p * 256;
            int row = s >> 5, c4 = (s & 31) << 2;
            *(float4*)&sW[row][c4] =
                *(const float4*)&w[(size_t)(c0 + row) * DOUT + c4];
        }
        __syncthreads();
#pragma unroll 4
        for (int cc = 0; cc < 64; ++cc) {
            float4 a0 = *(const float4*)&sInT[cc][ng * 8];       // broadcast
            float4 a1 = *(const float4*)&sInT[cc][ng * 8 + 4];   // broadcast
            float2 b = *(const float2*)&sW[cc][dp * 2];
            float av[8] = {a0.x, a0.y, a0.z, a0.w, a1.x, a1.y, a1.z, a1.w};
#pragma unroll
            for (int i = 0; i < 8; ++i) {
                acc[i][0] += av[i] * b.x;
                acc[i][1] += av[i] * b.y;
            }
        }
    }
    // store two uint4 fragments (8 n-elems each) in fragment order
#pragma unroll
    for (int j = 0; j < 2; ++j) {
        int d = dp * 2 + j;
        uint4 u;
        u.x = pk2(acc[0][j], acc[1][j]);
        u.y = pk2(acc[2][j], acc[3][j]);
        u.z = pk2(acc[4][j], acc[5][j]);
        u.w = pk2(acc[6][j], acc[7][j]);
        size_t off16 = ((size_t)blockIdx.x * 8 + (d >> 4)) * 64
                       + (ng * 16 + (d & 15));
        ((uint4*)xTf)[off16] = u;
    }
}

// ---------------------------------------------------------------------------
// Kernel 2: partial[sk][m][d] = sum_{k in split} adj[m][k] * x[k][d].
// LDS-FREE, BARRIER-FREE streaming MFMA: adj global->reg->cvt->A-frag,
// x read as pre-built B-fragments (1 KB coalesced uint4 per wave per tile).
// Block = 256 thr = 4 waves, wave w owns rows m0+w*16..+15, all 128 cols.
// Manual 2-stage register pipeline -> compiler emits counted vmcnt, never a
// full drain; ~20 loads/thread in flight. Grid = (256 row-tiles, SPLITK).
// ---------------------------------------------------------------------------
__global__ __launch_bounds__(256, 2) void adj_gemm_f(
        const float* __restrict__ adj, const unsigned short* __restrict__ xTf,
        float* __restrict__ part) {
    const int tid = threadIdx.x;
    const int w = tid >> 6;
    const int lane = tid & 63;
    const int lm = lane & 15;
    const int quad = lane >> 4;
    const int m0 = blockIdx.x * 64;
    const int sk = blockIdx.y;
    const int row = m0 + w * 16 + lm;

    const float* ap = adj + (size_t)row * NN + (size_t)sk * KHALF + quad * 8;
    const uint4* bp = (const uint4*)xTf + (size_t)sk * NK32 * 512 + lane;

    floatx4 acc[8];
#pragma unroll
    for (int t = 0; t < 8; ++t) acc[t] = (floatx4){0.f, 0.f, 0.f, 0.f};

    float4 a0A, a1A; uint4 bA[8];
    float4 a0B, a1B; uint4 bB[8];

#define LOADK(S, kk) do {                                                    \
        const float* _a = ap + (size_t)(kk) * 32;                            \
        a0##S = *(const float4*)_a;                                          \
        a1##S = *(const float4*)(_a + 4);                                    \
        const uint4* _b = bp + (size_t)(kk) * 512;                           \
        _Pragma("unroll")                                                    \
        for (int t = 0; t < 8; ++t) b##S[t] = _b[t * 64];                    \
    } while (0)

#define COMPUTE(S) do {                                                      \
        bf16x8 a;                                                            \
        a[0] = (__bf16)a0##S.x; a[1] = (__bf16)a0##S.y;                      \
        a[2] = (__bf16)a0##S.z; a[3] = (__bf16)a0##S.w;                      \
        a[4] = (__bf16)a1##S.x; a[5] = (__bf16)a1##S.y;                      \
        a[6] = (__bf16)a1##S.z; a[7] = (__bf16)a1##S.w;                      \
        _Pragma("unroll")                                                    \
        for (int t = 0; t < 8; ++t)                                          \
            acc[t] = __builtin_amdgcn_mfma_f32_16x16x32_bf16(                \
                a, __builtin_bit_cast(bf16x8, b##S[t]), acc[t], 0, 0, 0);    \
    } while (0)

    LOADK(A, 0);
    for (int k = 0; k < NK32; k += 2) {
        LOADK(B, k + 1);                       // issue next while computing
        COMPUTE(A);
        if (k + 2 < NK32) LOADK(A, k + 2);
        COMPUTE(B);
    }
#undef LOADK
#undef COMPUTE

    float* po = part + (size_t)sk * NN * DOUT;
#pragma unroll
    for (int t = 0; t < 8; ++t)
#pragma unroll
        for (int r = 0; r < 4; ++r)
            po[(size_t)(m0 + w * 16 + quad * 4 + r) * DOUT + t * 16 + lm] =
                acc[t][r];
}

// ---------------------------------------------------------------------------
// Kernel 3: out = partial[0] + partial[1]  (2M floats, ~24 MB traffic, ~6 us)
// ---------------------------------------------------------------------------
__global__ __launch_bounds__(256) void reduce_k(
        const float* __restrict__ part, float* __restrict__ out) {
    size_t i = (size_t)blockIdx.x * 256 + threadIdx.x;   // float4 index
    const float4* p0 = (const float4*)part;
    const float4* p1 = (const float4*)(part + (size_t)NN * DOUT);
    float4 a = p0[i], b = p1[i];
    float4 r = {a.x + b.x, a.y + b.y, a.z + b.z, a.w + b.w};
    ((float4*)out)[i] = r;
}

extern "C" void kernel_launch(void* const* d_in, const int* in_sizes, int n_in,
                              void* d_out, int out_size, void* d_ws, size_t ws_size,
                              hipStream_t stream) {
    const float* inputs  = (const float*)d_in[0];   // [16384][512]
    const float* adj     = (const float*)d_in[1];   // [16384][16384]
    const float* weights = (const float*)d_in[2];   // [512][128]
    float* out = (float*)d_out;                     // [16384][128]

    unsigned short* xTf = (unsigned short*)d_ws;              // 4 MiB fragments
    float* part = (float*)((char*)d_ws + (4u << 20));         // 2 x 8 MiB partials

    xw_kernel<<<NN / 32, 256, 0, stream>>>(inputs, weights, xTf);
    adj_gemm_f<<<dim3(NN / 64, SPLITK), 256, 0, stream>>>(adj, xTf, part);
    reduce_k<<<(NN * DOUT / 4) / 256, 256, 0, stream>>>(part, out);
}